// Round 1
// 15178.331 us; speedup vs baseline: 3.1764x; 3.1764x over previous
//
#include <hip/hip_runtime.h>
#include <hip/hip_bf16.h>
#include <math.h>

#define Dm 768
#define Hn 12
#define DEPTH 12
#define NPATCH 196
#define Ntok 197
#define MLPD 3072
#define NC 1000
#define Bb 32
#define BC 8            /* attention batch-chunk */
#define HD 64
#define SCALE 0.125f
#define TOKENS (Bb*Ntok)      /* 6304 */
#define NN (Ntok*Ntok)        /* 38809 */

typedef __hip_bfloat16 bf16;
typedef __attribute__((ext_vector_type(8))) short bf16x8;
typedef __attribute__((ext_vector_type(4))) float f32x4;

__device__ __forceinline__ float b2f(bf16 x){ return __bfloat162float(x); }
__device__ __forceinline__ float bits2f(unsigned short u){
  union { float f; unsigned int i; } cv; cv.i = ((unsigned int)u) << 16; return cv.f;
}
__device__ __forceinline__ float ldf(const float* p){ return *p; }
__device__ __forceinline__ float ldf(const bf16*  p){ return __bfloat162float(*p); }
__device__ __forceinline__ void  stf(float* p, float v){ *p = v; }
__device__ __forceinline__ void  stf(bf16*  p, float v){ *p = __float2bfloat16(v); }

// Runtime-dtype input accessor: f==1 -> bf16, f==0 -> fp32.
__device__ __forceinline__ float ldin(const void* p, long i, int f){
  return f ? __bfloat162float(((const bf16*)p)[i]) : ((const float*)p)[i];
}

// 4-contiguous-element load (fp32 or bf16 storage) -> float4
__device__ __forceinline__ float4 load4(const float* p){ return *(const float4*)p; }
__device__ __forceinline__ float4 load4(const bf16* p){
  ushort4 u = *(const ushort4*)p;
  float4 r; r.x = bits2f(u.x); r.y = bits2f(u.y); r.z = bits2f(u.z); r.w = bits2f(u.w);
  return r;
}

struct P23 { const void* p[23]; };

// ---- per-input dtype detection (fp32 low-half mantissas look like wild bf16
// exponents; fp32 ones-arrays show zeros exactly on even lanes) --------------
__global__ void detect_k(P23 ptrs, int* __restrict__ flags){
  int b = blockIdx.x;
  const unsigned short* u = (const unsigned short*)ptrs.p[b];
  int lane = threadIdx.x;
  unsigned short v = u[lane];
  int ex = (v >> 7) & 0xFF;
  bool bad = (ex > 140) || (ex != 0 && ex < 90);
  bool isz = (v == 0);
  unsigned long long bb = __ballot(bad);
  unsigned long long zb = __ballot(isz);
  if (lane == 0)
    flags[b] = (bb != 0ULL || zb == 0x5555555555555555ULL) ? 0 : 1;
}

// ---- patch extraction: x[B,3,224,224] -> xp[B*196, 768] fp32 ----------------
__global__ void patch_extract(const void* __restrict__ x, const int* __restrict__ F,
                              float* __restrict__ xp){
  int fx = F[0];
  int idx = blockIdx.x*256 + threadIdx.x;
  if (idx >= Bb*NPATCH*Dm) return;
  int k = idx % Dm;
  int t = idx / Dm;
  int p = t % NPATCH; int b = t / NPATCH;
  int c  = k >> 8;
  int r  = (k >> 4) & 15;
  int cc = k & 15;
  int pi = p / 14, pj = p % 14;
  long src = ((long)(b*3 + c)*224 + pi*16 + r)*224 + pj*16 + cc;
  xp[idx] = ldin(x, src, fx);
}

// ---- MFMA GEMM: C[M,N] = (A[M,K] @ W[N,K]^T) + bias -------------------------
// 128x128 tile, BK=32, 4 waves in 2x2, each wave 64x64 via 4x4 16x16x32 frags.
// A/W reg-staged into LDS as bf16 (runtime-dtype W). Row pad +8 bf16 -> 2-way
// bank aliasing max on ds_read_b128 (free per m136).
template<int ACT, bool ACCUM, typename TA, typename TC>
__global__ __launch_bounds__(256)
void gemm_mfma(const TA* __restrict__ A, int lda,
               const void* __restrict__ W, long woff, int ldw,
               const void* __restrict__ bias, long boff,
               const int* __restrict__ F, int wi, int bi,
               TC* __restrict__ C, int ldc,
               int M, int Ncols, int K)
{
  const int fw = F[wi];
  const int fb = (bi >= 0) ? F[bi] : 0;
  __shared__ __align__(16) bf16 As[128][40];
  __shared__ __align__(16) bf16 Ws[128][40];
  const int tid  = threadIdx.x;
  const int lane = tid & 63;
  const int wave = tid >> 6;
  const int mBase = blockIdx.y * 128;
  const int nBase = blockIdx.x * 128;
  const int wm = (wave >> 1) * 64;   // wave row offset in tile
  const int wn = (wave & 1)  * 64;   // wave col offset in tile
  const int lr = lane & 15;          // fragment row/col within 16
  const int lk = (lane >> 4) * 8;    // fragment k offset within 32
  const int sr = tid >> 3;           // staging row 0..31
  const int sc = (tid & 7) * 4;      // staging col 0..28

  f32x4 acc[4][4] = {};

  for (int k0 = 0; k0 < K; k0 += 32){
    #pragma unroll
    for (int i = 0; i < 4; i++){
      int rr = sr + i*32;
      // ---- A tile ----
      int gm = mBase + rr;
      float4 av = make_float4(0.f,0.f,0.f,0.f);
      if (gm < M) av = load4(&A[(long)gm*lda + k0 + sc]);
      As[rr][sc+0] = __float2bfloat16(av.x);
      As[rr][sc+1] = __float2bfloat16(av.y);
      As[rr][sc+2] = __float2bfloat16(av.z);
      As[rr][sc+3] = __float2bfloat16(av.w);
      // ---- W tile ----
      int gn = nBase + rr;
      float4 wv = make_float4(0.f,0.f,0.f,0.f);
      if (gn < Ncols){
        long off = woff + (long)gn*ldw + k0 + sc;
        if (fw){
          ushort4 u = *(const ushort4*)((const unsigned short*)W + off);
          wv.x = bits2f(u.x); wv.y = bits2f(u.y); wv.z = bits2f(u.z); wv.w = bits2f(u.w);
        } else {
          wv = *(const float4*)((const float*)W + off);
        }
      }
      Ws[rr][sc+0] = __float2bfloat16(wv.x);
      Ws[rr][sc+1] = __float2bfloat16(wv.y);
      Ws[rr][sc+2] = __float2bfloat16(wv.z);
      Ws[rr][sc+3] = __float2bfloat16(wv.w);
    }
    __syncthreads();
    bf16x8 af[4], bfr[4];
    #pragma unroll
    for (int mi = 0; mi < 4; mi++)
      af[mi] = *(const bf16x8*)&As[wm + mi*16 + lr][lk];
    #pragma unroll
    for (int ni = 0; ni < 4; ni++)
      bfr[ni] = *(const bf16x8*)&Ws[wn + ni*16 + lr][lk];
    #pragma unroll
    for (int mi = 0; mi < 4; mi++)
      #pragma unroll
      for (int ni = 0; ni < 4; ni++)
        acc[mi][ni] = __builtin_amdgcn_mfma_f32_16x16x32_bf16(af[mi], bfr[ni], acc[mi][ni], 0, 0, 0);
    __syncthreads();
  }

  // ---- epilogue: C/D layout col=lane&15, row=(lane>>4)*4+e ----
  const int cr = lane >> 4;
  float bv[4];
  #pragma unroll
  for (int ni = 0; ni < 4; ni++){
    int c = nBase + wn + ni*16 + lr;
    bv[ni] = (bi >= 0 && c < Ncols) ? ldin(bias, boff + c, fb) : 0.f;
  }
  #pragma unroll
  for (int mi = 0; mi < 4; mi++){
    #pragma unroll
    for (int e = 0; e < 4; e++){
      int rrow = mBase + wm + mi*16 + cr*4 + e;
      if (rrow >= M) continue;
      #pragma unroll
      for (int ni = 0; ni < 4; ni++){
        int c = nBase + wn + ni*16 + lr;
        if (c >= Ncols) continue;
        float v = acc[mi][ni][e] + bv[ni];
        if (ACT==1) v = 0.5f*v*(1.f + erff(v*0.70710678118f));
        if (ACCUM){ float* cp = (float*)&C[(long)rrow*ldc + c]; *cp += v; }
        else stf(&C[(long)rrow*ldc + c], v);
      }
    }
  }
}

// ---- assemble residual stream T from patch-embed + cls + pos ----------------
__global__ void assemble_t(const float* __restrict__ pe,
                           const void* __restrict__ bpe, const void* __restrict__ cls,
                           const void* __restrict__ pos, const int* __restrict__ F,
                           float* __restrict__ T)
{
  int f2 = F[2], f3 = F[3], f4 = F[4];
  int idx = blockIdx.x*256 + threadIdx.x;
  if (idx >= TOKENS*Dm) return;
  int d = idx % Dm;
  int t = idx / Dm;
  int n = t % Ntok, b = t / Ntok;
  float v;
  if (n == 0) v = ldin(cls, d, f3);
  else        v = pe[((long)b*NPATCH + n-1)*Dm + d] + ldin(bpe, d, f2);
  T[idx] = v + ldin(pos, (long)n*Dm + d, f4);
}

// ---- layernorm: one block per row, D=768 ------------------------------------
__global__ void layernorm(const float* __restrict__ X, long xstride,
                          const void* __restrict__ g, long goff, int gi,
                          const void* __restrict__ b, long boff, int bi,
                          const int* __restrict__ F,
                          float* __restrict__ Y, long ystride)
{
  int fg = F[gi], fb = F[bi];
  int row = blockIdx.x;
  const float* xr = X + (long)row*xstride;
  float* yr = Y + (long)row*ystride;
  int tid = threadIdx.x;
  float x0 = xr[tid], x1 = xr[tid+256], x2 = xr[tid+512];
  float s  = x0+x1+x2;
  float sq = x0*x0 + x1*x1 + x2*x2;
  __shared__ float red[6][2];
  for (int off=32; off; off>>=1){ s += __shfl_down(s, off); sq += __shfl_down(sq, off); }
  int wave = tid >> 6, lane = tid & 63;
  if (lane==0){ red[wave][0]=s; red[wave][1]=sq; }
  __syncthreads();
  if (tid==0){
    float S=0, SQ=0;
    for (int w=0;w<4;w++){ S+=red[w][0]; SQ+=red[w][1]; }
    red[4][0] = S*(1.f/768.f);
    red[4][1] = SQ*(1.f/768.f);
  }
  __syncthreads();
  float m  = red[4][0];
  float var= red[4][1] - m*m;
  float rs = rsqrtf(var + 1e-6f);
  yr[tid]     = (x0-m)*rs*ldin(g,goff+tid,fg)     + ldin(b,boff+tid,fb);
  yr[tid+256] = (x1-m)*rs*ldin(g,goff+tid+256,fg) + ldin(b,boff+tid+256,fb);
  yr[tid+512] = (x2-m)*rs*ldin(g,goff+tid+512,fg) + ldin(b,boff+tid+512,fb);
}

// ---- attention scores (batch-chunk): a[bl,h,n,m] = SCALE*q.k ----------------
__global__ void attn_scores(const bf16* __restrict__ QKV, bf16* __restrict__ A1,
                            int bbase){
  int z = blockIdx.z; int bl = z / Hn, h = z % Hn;
  int b = bbase + bl;
  int nBase = blockIdx.y*32, mBase = blockIdx.x*32;
  const bf16* Qb = QKV + (long)b*Ntok*2304 + h*HD;
  const bf16* Kb = QKV + (long)b*Ntok*2304 + Dm + h*HD;
  __shared__ float Qs[32][HD+1];
  __shared__ float Ks[32][HD+1];
  int tid = threadIdx.x;
  #pragma unroll
  for (int i=0;i<8;i++){
    int e = tid + i*256;
    int r = e >> 6, c = e & 63;
    int nq = nBase + r; Qs[r][c] = (nq < Ntok) ? b2f(Qb[(long)nq*2304 + c]) : 0.f;
    int nk = mBase + r; Ks[r][c] = (nk < Ntok) ? b2f(Kb[(long)nk*2304 + c]) : 0.f;
  }
  __syncthreads();
  int tx = tid & 15, ty = tid >> 4;
  float acc[2][2]={};
  #pragma unroll 8
  for (int kk=0; kk<64; kk++){
    float a0=Qs[ty][kk], a1=Qs[ty+16][kk];
    float b0=Ks[tx][kk], b1=Ks[tx+16][kk];
    acc[0][0]+=a0*b0; acc[0][1]+=a0*b1; acc[1][0]+=a1*b0; acc[1][1]+=a1*b1;
  }
  bf16* Ab = A1 + (long)z*NN;
  #pragma unroll
  for(int i=0;i<2;i++)
  #pragma unroll
  for(int j=0;j<2;j++){
    int n=nBase+ty+16*i, m=mBase+tx+16*j;
    if(n<Ntok && m<Ntok) Ab[(long)n*Ntok+m] = __float2bfloat16(SCALE*acc[i][j]);
  }
}

// ---- talking-heads mix IN PLACE over chunk: A[bl,g,:]=sum_h A[bl,h,:]W[g,h] -
__global__ void head_mix(bf16* __restrict__ A, const void* __restrict__ W,
                         long woff, int wi, const int* __restrict__ F){
  int fw = F[wi];
  long idx = (long)blockIdx.x*256 + threadIdx.x;
  if (idx >= (long)BC*NN) return;
  int bl = (int)(idx / NN); int rem = (int)(idx % NN);
  bf16* base = A + (long)bl*Hn*NN + rem;
  float vals[Hn];
  #pragma unroll
  for (int h=0; h<Hn; h++) vals[h] = b2f(base[(long)h*NN]);
  #pragma unroll
  for (int g=0; g<Hn; g++){
    float s = 0.f;
    #pragma unroll
    for (int h=0; h<Hn; h++) s += vals[h]*ldin(W, woff + g*Hn + h, fw);
    base[(long)g*NN] = __float2bfloat16(s);
  }
}

// ---- softmax over last dim (197), one wave per row, in place ----------------
__global__ void softmax_rows(bf16* __restrict__ A){
  long row = (long)blockIdx.x*4 + (threadIdx.x>>6);
  if (row >= (long)BC*Hn*Ntok) return;
  bf16* p = A + row*Ntok;
  int lane = threadIdx.x & 63;
  float v[4];
  float mx = -1e30f;
  #pragma unroll
  for (int j=0;j<4;j++){ int i = lane + j*64; v[j] = (i<Ntok)? b2f(p[i]) : -1e30f; mx = fmaxf(mx, v[j]); }
  for (int off=32; off; off>>=1) mx = fmaxf(mx, __shfl_xor(mx, off));
  float s = 0.f;
  #pragma unroll
  for (int j=0;j<4;j++){ v[j] = expf(v[j]-mx); s += v[j]; }
  for (int off=32; off; off>>=1) s += __shfl_xor(s, off);
  float inv = 1.f/s;
  #pragma unroll
  for (int j=0;j<4;j++){ int i = lane + j*64; if (i<Ntok) p[i] = __float2bfloat16(v[j]*inv); }
}

// ---- AV (batch-chunk): o[b,n,h*64+hd] = sum_m a[bl,h,n,m]*v[b,h,m,hd] -------
__global__ void attn_av(const bf16* __restrict__ A3, const bf16* __restrict__ QKV,
                        float* __restrict__ O, int bbase){
  int z = blockIdx.y; int bl = z/Hn, h = z%Hn;
  int b = bbase + bl;
  int nBase = blockIdx.x*32;
  const bf16* Ab = A3 + (long)z*NN;
  const bf16* Vb = QKV + (long)b*Ntok*2304 + 2*Dm + h*HD;
  __shared__ float As[32][33];
  __shared__ float Vs[32][HD];
  int tid = threadIdx.x;
  int hd = tid & 63, ty = tid >> 6;
  float acc[8] = {};
  for (int m0 = 0; m0 < Ntok; m0 += 32){
    #pragma unroll
    for (int i=0;i<4;i++){
      int e = tid + i*256; int r = e>>5, c = e&31;
      int n = nBase + r, m = m0 + c;
      As[r][c] = (n<Ntok && m<Ntok) ? b2f(Ab[(long)n*Ntok+m]) : 0.f;
    }
    #pragma unroll
    for (int i=0;i<8;i++){
      int e = tid + i*256; int r = e>>6, c = e&63;
      int m = m0 + r;
      Vs[r][c] = (m<Ntok) ? b2f(Vb[(long)m*2304 + c]) : 0.f;
    }
    __syncthreads();
    #pragma unroll
    for (int kk=0; kk<32; kk++){
      float bv = Vs[kk][hd];
      #pragma unroll
      for (int i=0;i<8;i++) acc[i] += As[ty + i*4][kk]*bv;
    }
    __syncthreads();
  }
  #pragma unroll
  for (int i=0;i<8;i++){
    int n = nBase + ty + i*4;
    if (n < Ntok) O[((long)(b*Ntok + n))*Dm + h*HD + hd] = acc[i];
  }
}

// ---- head: out[b,c] = lnf(t[b,0]) . head_w[c,:] + head_b[c]  (FP32 out) -----
__global__ void head_gemm(const float* __restrict__ HF, const void* __restrict__ Wh,
                          const void* __restrict__ bh_, const int* __restrict__ F,
                          float* __restrict__ out){
  int fw = F[21], fb = F[22];
  int b = blockIdx.y;
  int c = blockIdx.x*256 + threadIdx.x;
  __shared__ float hs[Dm];
  for (int i=threadIdx.x; i<Dm; i+=256) hs[i] = HF[(long)b*Dm+i];
  __syncthreads();
  if (c >= NC) return;
  float s = ldin(bh_, c, fb);
  for (int k=0;k<Dm;k++) s += hs[k]*ldin(Wh, (long)c*Dm + k, fw);
  out[b*NC + c] = s;
}

extern "C" void kernel_launch(void* const* d_in, const int* in_sizes, int n_in,
                              void* d_out, int out_size, void* d_ws, size_t ws_size,
                              hipStream_t stream)
{
  // ---- verify/remap inputs by element count (identity if order matches) ----
  static const int EXP[23] = {4816896, 589824, 768, 768, 151296, 9216, 9216,
                              21233664, 27648, 1728, 1728, 7077888, 9216, 9216,
                              9216, 28311552, 36864, 28311552, 9216, 768, 768,
                              768000, 1000};
  const void* in[23];
  bool ident = (n_in == 23);
  if (ident) for (int i = 0; i < 23; i++) if (in_sizes[i] != EXP[i]) { ident = false; break; }
  if (ident) {
    for (int i = 0; i < 23; i++) in[i] = d_in[i];
  } else {
    bool used[64] = {};
    for (int i = 0; i < 23; i++){
      in[i] = d_in[i < n_in ? i : 0];
      for (int j = 0; j < n_in && j < 64; j++)
        if (!used[j] && in_sizes[j] == EXP[i]) { in[i] = d_in[j]; used[j] = true; break; }
    }
  }

  float* out = (float*)d_out;   // reference output dtype is float32

  // ---- Compact workspace: total 77,463,808 B = 73.9 MiB ----
  char* base = (char*)d_ws;
  int*   Fl  = (int*)base;
  float* T   = (float*)(base + 256);
  float* Hb  = (float*)(base + 19366144L);
  char*  REST=  base + 38732032L;
  float* XP  = (float*)REST;
  bf16*  QKV = (bf16*)REST;
  bf16*  Aq  = (bf16*)(REST + 29048832L);
  bf16*  M1  = (bf16*)REST;

  P23 ptrs;
  for (int i = 0; i < 23; i++) ptrs.p[i] = in[i];
  detect_k<<<23, 64, 0, stream>>>(ptrs, Fl);

  // ---- patch embed ----
  patch_extract<<<(Bb*NPATCH*Dm+255)/256, 256, 0, stream>>>(in[0], Fl, XP);
  gemm_mfma<0,false,float,float><<<dim3(Dm/128, (Bb*NPATCH)/128), 256, 0, stream>>>(
      XP, Dm, in[1], 0, Dm, nullptr, 0, Fl, 1, -1, Hb, Dm, Bb*NPATCH, Dm, Dm);
  assemble_t<<<(TOKENS*Dm+255)/256, 256, 0, stream>>>(Hb, in[2], in[3], in[4], Fl, T);

  for (int L=0; L<DEPTH; L++){
    layernorm<<<TOKENS, 256, 0, stream>>>(T, Dm, in[5], (long)L*Dm, 5,
                                          in[6], (long)L*Dm, 6, Fl, Hb, Dm);
    gemm_mfma<0,false,float,bf16><<<dim3(2304/128, (TOKENS+127)/128), 256, 0, stream>>>(
        Hb, Dm, in[7], (long)L*2304*Dm, Dm, in[8], (long)L*2304, Fl, 7, 8,
        QKV, 2304, TOKENS, 2304, Dm);
    for (int cb = 0; cb < Bb/BC; cb++){
      int bbase = cb*BC;
      attn_scores<<<dim3(7,7,BC*Hn), 256, 0, stream>>>(QKV, Aq, bbase);
      head_mix<<<(int)(((long)BC*NN+255)/256), 256, 0, stream>>>(Aq, in[9], (long)L*Hn*Hn, 9, Fl);
      softmax_rows<<<(BC*Hn*Ntok+3)/4, 256, 0, stream>>>(Aq);
      head_mix<<<(int)(((long)BC*NN+255)/256), 256, 0, stream>>>(Aq, in[10], (long)L*Hn*Hn, 10, Fl);
      attn_av<<<dim3(7, BC*Hn), 256, 0, stream>>>(Aq, QKV, Hb, bbase);
    }
    gemm_mfma<0,true,float,float><<<dim3(Dm/128, (TOKENS+127)/128), 256, 0, stream>>>(
        Hb, Dm, in[11], (long)L*Dm*Dm, Dm, in[12], (long)L*Dm, Fl, 11, 12,
        T, Dm, TOKENS, Dm, Dm);
    layernorm<<<TOKENS, 256, 0, stream>>>(T, Dm, in[13], (long)L*Dm, 13,
                                          in[14], (long)L*Dm, 14, Fl, Hb, Dm);
    gemm_mfma<1,false,float,bf16><<<dim3(MLPD/128, (TOKENS+127)/128), 256, 0, stream>>>(
        Hb, Dm, in[15], (long)L*MLPD*Dm, Dm, in[16], (long)L*MLPD, Fl, 15, 16,
        M1, MLPD, TOKENS, MLPD, Dm);
    gemm_mfma<0,true,bf16,float><<<dim3(Dm/128, (TOKENS+127)/128), 256, 0, stream>>>(
        M1, MLPD, in[17], (long)L*Dm*MLPD, MLPD, in[18], (long)L*Dm, Fl, 17, 18,
        T, Dm, TOKENS, Dm, MLPD);
  }

  layernorm<<<Bb, 256, 0, stream>>>(T, (long)Ntok*Dm, in[19], 0, 19,
                                    in[20], 0, 20, Fl, Hb, Dm);
  head_gemm<<<dim3((NC+255)/256, Bb), 256, 0, stream>>>(Hb, in[21], in[22], Fl, out);
}

// Round 2
// 12015.382 us; speedup vs baseline: 4.0125x; 1.2632x over previous
//
#include <hip/hip_runtime.h>
#include <hip/hip_bf16.h>
#include <math.h>

#define Dm 768
#define Hn 12
#define DEPTH 12
#define NPATCH 196
#define Ntok 197
#define MLPD 3072
#define NC 1000
#define Bb 32
#define HD 64
#define SCALE 0.125f
#define TOKENS (Bb*Ntok)      /* 6304 */

typedef __hip_bfloat16 bf16;
typedef __attribute__((ext_vector_type(8))) short bf16x8;
typedef __attribute__((ext_vector_type(4))) float f32x4;

__device__ __forceinline__ float b2f(bf16 x){ return __bfloat162float(x); }
__device__ __forceinline__ float bits2f(unsigned short u){
  union { float f; unsigned int i; } cv; cv.i = ((unsigned int)u) << 16; return cv.f;
}
__device__ __forceinline__ float ldf(const float* p){ return *p; }
__device__ __forceinline__ float ldf(const bf16*  p){ return __bfloat162float(*p); }
__device__ __forceinline__ void  stf(float* p, float v){ *p = v; }
__device__ __forceinline__ void  stf(bf16*  p, float v){ *p = __float2bfloat16(v); }

// Runtime-dtype input accessor: f==1 -> bf16, f==0 -> fp32.
__device__ __forceinline__ float ldin(const void* p, long i, int f){
  return f ? __bfloat162float(((const bf16*)p)[i]) : ((const float*)p)[i];
}

// 4-contiguous-element load (fp32 or bf16 storage) -> float4
__device__ __forceinline__ float4 load4(const float* p){ return *(const float4*)p; }
__device__ __forceinline__ float4 load4(const bf16* p){
  ushort4 u = *(const ushort4*)p;
  float4 r; r.x = bits2f(u.x); r.y = bits2f(u.y); r.z = bits2f(u.z); r.w = bits2f(u.w);
  return r;
}
__device__ __forceinline__ unsigned short f2bfu(float v){
  bf16 b = __float2bfloat16(v);
  return *(unsigned short*)&b;
}

struct P23 { const void* p[23]; };

// ---- per-input dtype detection ---------------------------------------------
__global__ void detect_k(P23 ptrs, int* __restrict__ flags){
  int b = blockIdx.x;
  const unsigned short* u = (const unsigned short*)ptrs.p[b];
  int lane = threadIdx.x;
  unsigned short v = u[lane];
  int ex = (v >> 7) & 0xFF;
  bool bad = (ex > 140) || (ex != 0 && ex < 90);
  bool isz = (v == 0);
  unsigned long long bb = __ballot(bad);
  unsigned long long zb = __ballot(isz);
  if (lane == 0)
    flags[b] = (bb != 0ULL || zb == 0x5555555555555555ULL) ? 0 : 1;
}

// ---- patch extraction: x[B,3,224,224] -> xp[B*196, 768] fp32 ----------------
__global__ void patch_extract(const void* __restrict__ x, const int* __restrict__ F,
                              float* __restrict__ xp){
  int fx = F[0];
  int idx = blockIdx.x*256 + threadIdx.x;
  if (idx >= Bb*NPATCH*Dm) return;
  int k = idx % Dm;
  int t = idx / Dm;
  int p = t % NPATCH; int b = t / NPATCH;
  int c  = k >> 8;
  int r  = (k >> 4) & 15;
  int cc = k & 15;
  int pi = p / 14, pj = p % 14;
  long src = ((long)(b*3 + c)*224 + pi*16 + r)*224 + pj*16 + cc;
  xp[idx] = ldin(x, src, fx);
}

// ---- MFMA GEMM: C[M,N] = (A[M,K] @ W[N,K]^T) + bias -------------------------
template<int ACT, bool ACCUM, typename TA, typename TC>
__global__ __launch_bounds__(256)
void gemm_mfma(const TA* __restrict__ A, int lda,
               const void* __restrict__ W, long woff, int ldw,
               const void* __restrict__ bias, long boff,
               const int* __restrict__ F, int wi, int bi,
               TC* __restrict__ C, int ldc,
               int M, int Ncols, int K)
{
  const int fw = F[wi];
  const int fb = (bi >= 0) ? F[bi] : 0;
  __shared__ __align__(16) bf16 As[128][40];
  __shared__ __align__(16) bf16 Ws[128][40];
  const int tid  = threadIdx.x;
  const int lane = tid & 63;
  const int wave = tid >> 6;
  const int mBase = blockIdx.y * 128;
  const int nBase = blockIdx.x * 128;
  const int wm = (wave >> 1) * 64;
  const int wn = (wave & 1)  * 64;
  const int lr = lane & 15;
  const int lk = (lane >> 4) * 8;
  const int sr = tid >> 3;
  const int sc = (tid & 7) * 4;

  f32x4 acc[4][4] = {};

  for (int k0 = 0; k0 < K; k0 += 32){
    #pragma unroll
    for (int i = 0; i < 4; i++){
      int rr = sr + i*32;
      int gm = mBase + rr;
      float4 av = make_float4(0.f,0.f,0.f,0.f);
      if (gm < M) av = load4(&A[(long)gm*lda + k0 + sc]);
      union { ushort4 u4; unsigned short u[4]; } pa;
      pa.u[0]=f2bfu(av.x); pa.u[1]=f2bfu(av.y); pa.u[2]=f2bfu(av.z); pa.u[3]=f2bfu(av.w);
      *(ushort4*)&As[rr][sc] = pa.u4;
      int gn = nBase + rr;
      float4 wv = make_float4(0.f,0.f,0.f,0.f);
      if (gn < Ncols){
        long off = woff + (long)gn*ldw + k0 + sc;
        if (fw){
          ushort4 u = *(const ushort4*)((const unsigned short*)W + off);
          wv.x = bits2f(u.x); wv.y = bits2f(u.y); wv.z = bits2f(u.z); wv.w = bits2f(u.w);
        } else {
          wv = *(const float4*)((const float*)W + off);
        }
      }
      union { ushort4 u4; unsigned short u[4]; } pw;
      pw.u[0]=f2bfu(wv.x); pw.u[1]=f2bfu(wv.y); pw.u[2]=f2bfu(wv.z); pw.u[3]=f2bfu(wv.w);
      *(ushort4*)&Ws[rr][sc] = pw.u4;
    }
    __syncthreads();
    bf16x8 af[4], bfr[4];
    #pragma unroll
    for (int mi = 0; mi < 4; mi++)
      af[mi] = *(const bf16x8*)&As[wm + mi*16 + lr][lk];
    #pragma unroll
    for (int ni = 0; ni < 4; ni++)
      bfr[ni] = *(const bf16x8*)&Ws[wn + ni*16 + lr][lk];
    #pragma unroll
    for (int mi = 0; mi < 4; mi++)
      #pragma unroll
      for (int ni = 0; ni < 4; ni++)
        acc[mi][ni] = __builtin_amdgcn_mfma_f32_16x16x32_bf16(af[mi], bfr[ni], acc[mi][ni], 0, 0, 0);
    __syncthreads();
  }

  const int cr = lane >> 4;
  float bv[4];
  #pragma unroll
  for (int ni = 0; ni < 4; ni++){
    int c = nBase + wn + ni*16 + lr;
    bv[ni] = (bi >= 0 && c < Ncols) ? ldin(bias, boff + c, fb) : 0.f;
  }
  #pragma unroll
  for (int mi = 0; mi < 4; mi++){
    #pragma unroll
    for (int e = 0; e < 4; e++){
      int rrow = mBase + wm + mi*16 + cr*4 + e;
      if (rrow >= M) continue;
      #pragma unroll
      for (int ni = 0; ni < 4; ni++){
        int c = nBase + wn + ni*16 + lr;
        if (c >= Ncols) continue;
        float v = acc[mi][ni][e] + bv[ni];
        if (ACT==1) v = 0.5f*v*(1.f + erff(v*0.70710678118f));
        if (ACCUM){ float* cp = (float*)&C[(long)rrow*ldc + c]; *cp += v; }
        else stf(&C[(long)rrow*ldc + c], v);
      }
    }
  }
}

// ---- assemble residual stream ----------------------------------------------
__global__ void assemble_t(const float* __restrict__ pe,
                           const void* __restrict__ bpe, const void* __restrict__ cls,
                           const void* __restrict__ pos, const int* __restrict__ F,
                           float* __restrict__ T)
{
  int f2 = F[2], f3 = F[3], f4 = F[4];
  int idx = blockIdx.x*256 + threadIdx.x;
  if (idx >= TOKENS*Dm) return;
  int d = idx % Dm;
  int t = idx / Dm;
  int n = t % Ntok, b = t / Ntok;
  float v;
  if (n == 0) v = ldin(cls, d, f3);
  else        v = pe[((long)b*NPATCH + n-1)*Dm + d] + ldin(bpe, d, f2);
  T[idx] = v + ldin(pos, (long)n*Dm + d, f4);
}

// ---- layernorm --------------------------------------------------------------
__global__ void layernorm(const float* __restrict__ X, long xstride,
                          const void* __restrict__ g, long goff, int gi,
                          const void* __restrict__ b, long boff, int bi,
                          const int* __restrict__ F,
                          float* __restrict__ Y, long ystride)
{
  int fg = F[gi], fb = F[bi];
  int row = blockIdx.x;
  const float* xr = X + (long)row*xstride;
  float* yr = Y + (long)row*ystride;
  int tid = threadIdx.x;
  float x0 = xr[tid], x1 = xr[tid+256], x2 = xr[tid+512];
  float s  = x0+x1+x2;
  float sq = x0*x0 + x1*x1 + x2*x2;
  __shared__ float red[6][2];
  for (int off=32; off; off>>=1){ s += __shfl_down(s, off); sq += __shfl_down(sq, off); }
  int wave = tid >> 6, lane = tid & 63;
  if (lane==0){ red[wave][0]=s; red[wave][1]=sq; }
  __syncthreads();
  if (tid==0){
    float S=0, SQ=0;
    for (int w=0;w<4;w++){ S+=red[w][0]; SQ+=red[w][1]; }
    red[4][0] = S*(1.f/768.f);
    red[4][1] = SQ*(1.f/768.f);
  }
  __syncthreads();
  float m  = red[4][0];
  float var= red[4][1] - m*m;
  float rs = rsqrtf(var + 1e-6f);
  yr[tid]     = (x0-m)*rs*ldin(g,goff+tid,fg)     + ldin(b,boff+tid,fb);
  yr[tid+256] = (x1-m)*rs*ldin(g,goff+tid+256,fg) + ldin(b,boff+tid+256,fb);
  yr[tid+512] = (x2-m)*rs*ldin(g,goff+tid+512,fg) + ldin(b,boff+tid+512,fb);
}

// ---- fused talking-heads attention ------------------------------------------
// One block per (n-tile of 16, image b). 4 waves x 3 heads each.
// S[12][16][232] bf16 holds the full score rows; mixes+softmax in LDS;
// scores & AV via mfma_16x16x32 with K/V fetched from global / swizzled LDS.
#define SMP 232            /* m-pad: 464B row stride, 16B aligned, bank step 20 */
#define VROW 776           /* V LDS row: 1552B, 16B aligned */

__device__ __forceinline__ void mix12(bf16 (*S)[16][SMP], const void* W, long woff,
                                      int fw, int tid){
  float wf[12][12];
  #pragma unroll
  for (int g=0; g<12; g++)
    #pragma unroll
    for (int h=0; h<12; h++) wf[g][h] = ldin(W, woff + g*12 + h, fw);
  for (int it=0; it<13; it++){
    int p = it*256 + tid;          // 13*256 = 3328 = 16*208
    int n = p / 208, m = p - n*208;
    float vals[12];
    #pragma unroll
    for (int h=0; h<12; h++) vals[h] = b2f(S[h][n][m]);
    #pragma unroll
    for (int g=0; g<12; g++){
      float s = 0.f;
      #pragma unroll
      for (int h=0; h<12; h++) s += vals[h]*wf[g][h];
      S[g][n][m] = __float2bfloat16(s);
    }
  }
}

__global__ __launch_bounds__(256, 1)
void attn_fused(const bf16* __restrict__ QKV,
                const void* __restrict__ Wpre, const void* __restrict__ Wpost,
                long woff, const int* __restrict__ F, float* __restrict__ O)
{
  __shared__ __align__(16) bf16 S[12][16][SMP];     // 89,088 B
  __shared__ __align__(16) bf16 Vl[32][VROW];       // 49,664 B
  const int b  = blockIdx.y;
  const int n0 = blockIdx.x * 16;
  const int tid = threadIdx.x, lane = tid & 63, wave = tid >> 6;
  const int lr = lane & 15, lg = lane >> 4;
  const bf16* Qb = QKV + (long)b*Ntok*2304;

  // zero S (pads must be exactly 0)
  {
    bf16x8 z = {};
    bf16x8* sp = (bf16x8*)S;
    for (int i = tid; i < (12*16*SMP)/8; i += 256) sp[i] = z;
  }

  // Q fragments (A-frag: row=n0+lr, k=lg*8+j), 3 heads x 2 k-frags, zero-pad n
  bf16x8 qf[3][2] = {};
  int nq = n0 + lr;
  if (nq < Ntok){
    #pragma unroll
    for (int hh=0; hh<3; hh++){
      int h = wave*3 + hh;
      qf[hh][0] = *(const bf16x8*)(Qb + (long)nq*2304 + h*64 +      lg*8);
      qf[hh][1] = *(const bf16x8*)(Qb + (long)nq*2304 + h*64 + 32 + lg*8);
    }
  }
  __syncthreads();

  // ---- phase 1: scores S[h][n][m] = SCALE * q.k ----
  {
    const bf16* Kb = Qb + Dm;
    int mq = 0;
    for (int mt=0; mt<13; mt++){
      mq = mt*16 + lr;
      bool mok = (mq < Ntok);
      #pragma unroll
      for (int hh=0; hh<3; hh++){
        int h = wave*3 + hh;
        bf16x8 k0 = {}, k1 = {};
        if (mok){
          k0 = *(const bf16x8*)(Kb + (long)mq*2304 + h*64 +      lg*8);
          k1 = *(const bf16x8*)(Kb + (long)mq*2304 + h*64 + 32 + lg*8);
        }
        f32x4 acc = {};
        acc = __builtin_amdgcn_mfma_f32_16x16x32_bf16(qf[hh][0], k0, acc, 0,0,0);
        acc = __builtin_amdgcn_mfma_f32_16x16x32_bf16(qf[hh][1], k1, acc, 0,0,0);
        #pragma unroll
        for (int e=0; e<4; e++)
          S[h][lg*4+e][mt*16+lr] = __float2bfloat16(SCALE*acc[e]);
      }
    }
  }
  __syncthreads();

  // ---- phase 2: pre-softmax talking-heads mix ----
  mix12(S, Wpre, woff, F[9], tid);
  __syncthreads();

  // ---- phase 3: softmax per (g, n) row over m<197 ----
  for (int i=0; i<48; i++){
    int r = wave*48 + i;
    int g = r >> 4, nl = r & 15;
    if (n0 + nl >= Ntok) continue;       // uniform across wave
    float v[4]; float mx = -1e30f;
    #pragma unroll
    for (int j=0; j<4; j++){
      int m = lane + j*64;
      v[j] = (m < Ntok) ? b2f(S[g][nl][m]) : -1e30f;
      mx = fmaxf(mx, v[j]);
    }
    for (int off=32; off; off>>=1) mx = fmaxf(mx, __shfl_xor(mx, off));
    float s = 0.f;
    #pragma unroll
    for (int j=0; j<4; j++){ v[j] = __expf(v[j]-mx); s += v[j]; }
    for (int off=32; off; off>>=1) s += __shfl_xor(s, off);
    float inv = 1.f/s;
    #pragma unroll
    for (int j=0; j<4; j++){
      int m = lane + j*64;
      if (m < Ntok) S[g][nl][m] = __float2bfloat16(v[j]*inv);
    }
  }
  __syncthreads();

  // ---- phase 4: post-softmax mix ----
  mix12(S, Wpost, woff, F[10], tid);
  __syncthreads();

  // ---- phase 5: AV, accumulate over m in chunks of 32 ----
  const bf16* Vg = Qb + 2*Dm;
  f32x4 avacc[3][4] = {};
  for (int mc=0; mc<7; mc++){
    int m0 = mc*32;
    // stage V chunk [32][768] -> Vl with XOR swizzle on byte bits 5-6 keyed m>>3
    for (int it=0; it<12; it++){
      int e = it*64 + lane;                 // 0..767 per wave
      int ml = wave*8 + e/96;               // local row 0..31
      int grp = e - (e/96)*96;              // 0..95 -> d = grp*8
      int mg = m0 + ml;
      bf16x8 v = {};
      if (mg < Ntok) v = *(const bf16x8*)(Vg + (long)mg*2304 + grp*8);
      int off = ml*(VROW*2) + grp*16;
      off ^= ((ml>>3)&3) << 5;
      *(bf16x8*)((char*)Vl + off) = v;
    }
    __syncthreads();
    #pragma unroll
    for (int hh=0; hh<3; hh++){
      int h = wave*3 + hh;
      // A-frag: P[h][lr][m0 + lg*8 .. +7] contiguous b128
      bf16x8 af = *(const bf16x8*)&S[h][lr][m0 + lg*8];
      #pragma unroll
      for (int dt=0; dt<4; dt++){
        int dcol = h*64 + dt*16 + lr;
        bf16x8 bfv;
        #pragma unroll
        for (int j=0; j<8; j++){
          int ml = lg*8 + j;
          int off = ml*(VROW*2) + dcol*2;
          off ^= ((ml>>3)&3) << 5;
          bfv[j] = *(short*)((char*)Vl + off);
        }
        avacc[hh][dt] = __builtin_amdgcn_mfma_f32_16x16x32_bf16(af, bfv, avacc[hh][dt], 0,0,0);
      }
    }
    __syncthreads();
  }

  // ---- epilogue: O[b*197+n][h*64+d] ----
  #pragma unroll
  for (int hh=0; hh<3; hh++){
    int h = wave*3 + hh;
    #pragma unroll
    for (int dt=0; dt<4; dt++){
      #pragma unroll
      for (int e=0; e<4; e++){
        int n = n0 + lg*4 + e;
        if (n < Ntok)
          O[((long)(b*Ntok + n))*Dm + h*64 + dt*16 + lr] = avacc[hh][dt][e];
      }
    }
  }
}

// ---- head: out[b,c] = lnf(t[b,0]) . head_w[c,:] + head_b[c] -----------------
__global__ void head_gemm(const float* __restrict__ HF, const void* __restrict__ Wh,
                          const void* __restrict__ bh_, const int* __restrict__ F,
                          float* __restrict__ out){
  int fw = F[21], fb = F[22];
  int b = blockIdx.y;
  int c = blockIdx.x*256 + threadIdx.x;
  __shared__ float hs[Dm];
  for (int i=threadIdx.x; i<Dm; i+=256) hs[i] = HF[(long)b*Dm+i];
  __syncthreads();
  if (c >= NC) return;
  float s = ldin(bh_, c, fb);
  for (int k=0;k<Dm;k++) s += hs[k]*ldin(Wh, (long)c*Dm + k, fw);
  out[b*NC + c] = s;
}

extern "C" void kernel_launch(void* const* d_in, const int* in_sizes, int n_in,
                              void* d_out, int out_size, void* d_ws, size_t ws_size,
                              hipStream_t stream)
{
  static const int EXP[23] = {4816896, 589824, 768, 768, 151296, 9216, 9216,
                              21233664, 27648, 1728, 1728, 7077888, 9216, 9216,
                              9216, 28311552, 36864, 28311552, 9216, 768, 768,
                              768000, 1000};
  const void* in[23];
  bool ident = (n_in == 23);
  if (ident) for (int i = 0; i < 23; i++) if (in_sizes[i] != EXP[i]) { ident = false; break; }
  if (ident) {
    for (int i = 0; i < 23; i++) in[i] = d_in[i];
  } else {
    bool used[64] = {};
    for (int i = 0; i < 23; i++){
      in[i] = d_in[i < n_in ? i : 0];
      for (int j = 0; j < n_in && j < 64; j++)
        if (!used[j] && in_sizes[j] == EXP[i]) { in[i] = d_in[j]; used[j] = true; break; }
    }
  }

  float* out = (float*)d_out;

  char* base = (char*)d_ws;
  int*   Fl  = (int*)base;
  float* T   = (float*)(base + 256);
  float* Hb  = (float*)(base + 19366144L);
  char*  REST=  base + 38732032L;
  float* XP  = (float*)REST;
  bf16*  QKV = (bf16*)REST;
  bf16*  M1  = (bf16*)REST;

  P23 ptrs;
  for (int i = 0; i < 23; i++) ptrs.p[i] = in[i];
  detect_k<<<23, 64, 0, stream>>>(ptrs, Fl);

  patch_extract<<<(Bb*NPATCH*Dm+255)/256, 256, 0, stream>>>(in[0], Fl, XP);
  gemm_mfma<0,false,float,float><<<dim3(Dm/128, (Bb*NPATCH)/128), 256, 0, stream>>>(
      XP, Dm, in[1], 0, Dm, nullptr, 0, Fl, 1, -1, Hb, Dm, Bb*NPATCH, Dm, Dm);
  assemble_t<<<(TOKENS*Dm+255)/256, 256, 0, stream>>>(Hb, in[2], in[3], in[4], Fl, T);

  for (int L=0; L<DEPTH; L++){
    layernorm<<<TOKENS, 256, 0, stream>>>(T, Dm, in[5], (long)L*Dm, 5,
                                          in[6], (long)L*Dm, 6, Fl, Hb, Dm);
    gemm_mfma<0,false,float,bf16><<<dim3(2304/128, (TOKENS+127)/128), 256, 0, stream>>>(
        Hb, Dm, in[7], (long)L*2304*Dm, Dm, in[8], (long)L*2304, Fl, 7, 8,
        QKV, 2304, TOKENS, 2304, Dm);
    attn_fused<<<dim3(13, Bb), 256, 0, stream>>>(QKV, in[9], in[10],
                                                 (long)L*Hn*Hn, Fl, Hb);
    gemm_mfma<0,true,float,float><<<dim3(Dm/128, (TOKENS+127)/128), 256, 0, stream>>>(
        Hb, Dm, in[11], (long)L*Dm*Dm, Dm, in[12], (long)L*Dm, Fl, 11, 12,
        T, Dm, TOKENS, Dm, Dm);
    layernorm<<<TOKENS, 256, 0, stream>>>(T, Dm, in[13], (long)L*Dm, 13,
                                          in[14], (long)L*Dm, 14, Fl, Hb, Dm);
    gemm_mfma<1,false,float,bf16><<<dim3(MLPD/128, (TOKENS+127)/128), 256, 0, stream>>>(
        Hb, Dm, in[15], (long)L*MLPD*Dm, Dm, in[16], (long)L*MLPD, Fl, 15, 16,
        M1, MLPD, TOKENS, MLPD, Dm);
    gemm_mfma<0,true,bf16,float><<<dim3(Dm/128, (TOKENS+127)/128), 256, 0, stream>>>(
        M1, MLPD, in[17], (long)L*Dm*MLPD, MLPD, in[18], (long)L*Dm, Fl, 17, 18,
        T, Dm, TOKENS, Dm, MLPD);
  }

  layernorm<<<Bb, 256, 0, stream>>>(T, (long)Ntok*Dm, in[19], 0, 19,
                                    in[20], 0, 20, Fl, Hb, Dm);
  head_gemm<<<dim3((NC+255)/256, Bb), 256, 0, stream>>>(Hb, in[21], in[22], Fl, out);
}

// Round 4
// 10514.238 us; speedup vs baseline: 4.5854x; 1.1428x over previous
//
#include <hip/hip_runtime.h>
#include <hip/hip_bf16.h>
#include <math.h>

#define Dm 768
#define Hn 12
#define DEPTH 12
#define NPATCH 196
#define Ntok 197
#define MLPD 3072
#define NC 1000
#define Bb 32
#define HD 64
#define SCALE 0.125f
#define TOKENS (Bb*Ntok)      /* 6304 */

typedef __hip_bfloat16 bf16;
typedef __attribute__((ext_vector_type(8))) short bf16x8;
typedef __attribute__((ext_vector_type(4))) float f32x4;

__device__ __forceinline__ float b2f(bf16 x){ return __bfloat162float(x); }
__device__ __forceinline__ float bits2f(unsigned short u){
  union { float f; unsigned int i; } cv; cv.i = ((unsigned int)u) << 16; return cv.f;
}
__device__ __forceinline__ float ldf(const float* p){ return *p; }
__device__ __forceinline__ float ldf(const bf16*  p){ return __bfloat162float(*p); }
__device__ __forceinline__ void  stf(float* p, float v){ *p = v; }
__device__ __forceinline__ void  stf(bf16*  p, float v){ *p = __float2bfloat16(v); }

// Runtime-dtype input accessor: f==1 -> bf16, f==0 -> fp32.
__device__ __forceinline__ float ldin(const void* p, long i, int f){
  return f ? __bfloat162float(((const bf16*)p)[i]) : ((const float*)p)[i];
}

__device__ __forceinline__ unsigned short f2bfu(float v){
  bf16 b = __float2bfloat16(v);
  return *(unsigned short*)&b;
}
__device__ __forceinline__ bf16x8 pack8(const float4& a, const float4& b){
  bf16x8 r;
  r[0]=(short)f2bfu(a.x); r[1]=(short)f2bfu(a.y); r[2]=(short)f2bfu(a.z); r[3]=(short)f2bfu(a.w);
  r[4]=(short)f2bfu(b.x); r[5]=(short)f2bfu(b.y); r[6]=(short)f2bfu(b.z); r[7]=(short)f2bfu(b.w);
  return r;
}

struct P23 { const void* p[23]; };

// ---- per-input dtype detection ---------------------------------------------
__global__ void detect_k(P23 ptrs, int* __restrict__ flags){
  int b = blockIdx.x;
  const unsigned short* u = (const unsigned short*)ptrs.p[b];
  int lane = threadIdx.x;
  unsigned short v = u[lane];
  int ex = (v >> 7) & 0xFF;
  bool bad = (ex > 140) || (ex != 0 && ex < 90);
  bool isz = (v == 0);
  unsigned long long bb = __ballot(bad);
  unsigned long long zb = __ballot(isz);
  if (lane == 0)
    flags[b] = (bb != 0ULL || zb == 0x5555555555555555ULL) ? 0 : 1;
}

// ---- patch extraction: x[B,3,224,224] -> xp[B*196, 768] fp32 ----------------
__global__ void patch_extract(const void* __restrict__ x, const int* __restrict__ F,
                              float* __restrict__ xp){
  int fx = F[0];
  int idx = blockIdx.x*256 + threadIdx.x;
  if (idx >= Bb*NPATCH*Dm) return;
  int k = idx % Dm;
  int t = idx / Dm;
  int p = t % NPATCH; int b = t / NPATCH;
  int c  = k >> 8;
  int r  = (k >> 4) & 15;
  int cc = k & 15;
  int pi = p / 14, pj = p % 14;
  long src = ((long)(b*3 + c)*224 + pi*16 + r)*224 + pj*16 + cc;
  xp[idx] = ldin(x, src, fx);
}

// ---- MFMA GEMM: C[M,N] = (A[M,K] @ W[N,K]^T) + bias -------------------------
// Double-buffered LDS, BK=64, reg-staged (dtype-converting). LDS row stride
// 72 elem = 144B = 9x16B (odd) -> 16B read/write bank-groups (row+slot)%8 are
// perfectly balanced: conflict-free. Tile BMxBN templated: 128x128 for big-N,
// 64x64 for N=768 (grid 1188 blocks -> 4 blocks/CU, latency hidden by TLP).
template<int BM, int BN, int ACT, bool ACCUM, typename TA, typename TC>
__global__ __launch_bounds__(256)
void gemm_mfma(const TA* __restrict__ A, int lda,
               const void* __restrict__ W, long woff, int ldw,
               const void* __restrict__ bias, long boff,
               const int* __restrict__ F, int wi, int bi,
               TC* __restrict__ C, int ldc,
               int M, int Ncols, int K)
{
  constexpr int FR = BM/32;            // 16x16 frags per wave (M)
  constexpr int FC = BN/32;            // frags per wave (N)
  constexpr int NVA = BM/32;           // 8-elem staging vectors per thread (A)
  constexpr int NVW = BN/32;
  constexpr int LR = 72;               // LDS row stride (elements)
  constexpr bool AF32 = (sizeof(TA) == 4);
  __shared__ __align__(16) bf16 LDS_[2*(BM+BN)*LR];

  const int fw = F[wi];
  const int fb = (bi >= 0) ? F[bi] : 0;
  const int tid = threadIdx.x, lane = tid & 63, wave = tid >> 6;
  const int mBase = blockIdx.y*BM, nBase = blockIdx.x*BN;
  const int wm = (wave >> 1)*(BM/2), wn = (wave & 1)*(BN/2);
  const int lr = lane & 15, lg = lane >> 4;
  const int srow = tid >> 3, scol = (tid & 7)*8;

  f32x4 acc[FR][FC] = {};

  float4 raf[NVA][2]; bf16x8 rah[NVA];
  float4 rwf[NVW][2]; bf16x8 rwh[NVW];

  auto LOADT = [&](int kt){
    int k0 = kt*64 + scol;
    #pragma unroll
    for (int i = 0; i < NVA; i++){
      int gm = mBase + srow + i*32;
      if constexpr (AF32){
        raf[i][0] = make_float4(0.f,0.f,0.f,0.f);
        raf[i][1] = make_float4(0.f,0.f,0.f,0.f);
        if (gm < M){
          const float* p = (const float*)A + (long)gm*lda + k0;
          raf[i][0] = *(const float4*)p;
          raf[i][1] = *(const float4*)(p+4);
        }
      } else {
        rah[i] = (bf16x8){};
        if (gm < M) rah[i] = *(const bf16x8*)((const bf16*)A + (long)gm*lda + k0);
      }
    }
    #pragma unroll
    for (int i = 0; i < NVW; i++){
      int gn = nBase + srow + i*32;
      if (fw){
        rwh[i] = (bf16x8){};
        if (gn < Ncols)
          rwh[i] = *(const bf16x8*)((const unsigned short*)W + woff + (long)gn*ldw + k0);
      } else {
        rwf[i][0] = make_float4(0.f,0.f,0.f,0.f);
        rwf[i][1] = make_float4(0.f,0.f,0.f,0.f);
        if (gn < Ncols){
          const float* p = (const float*)W + woff + (long)gn*ldw + k0;
          rwf[i][0] = *(const float4*)p;
          rwf[i][1] = *(const float4*)(p+4);
        }
      }
    }
  };

  auto WRITE = [&](int buf){
    #pragma unroll
    for (int i = 0; i < NVA; i++){
      int r = srow + i*32;
      bf16x8 v;
      if constexpr (AF32) v = pack8(raf[i][0], raf[i][1]);
      else                v = rah[i];
      *(bf16x8*)&LDS_[buf*(BM*LR) + r*LR + scol] = v;
    }
    #pragma unroll
    for (int i = 0; i < NVW; i++){
      int r = srow + i*32;
      bf16x8 v;
      if (fw) v = rwh[i];
      else    v = pack8(rwf[i][0], rwf[i][1]);
      *(bf16x8*)&LDS_[2*BM*LR + buf*(BN*LR) + r*LR + scol] = v;
    }
  };

  auto COMPUTE = [&](int buf){
    #pragma unroll
    for (int kk = 0; kk < 2; kk++){
      bf16x8 af[FR], bfv[FC];
      #pragma unroll
      for (int mi = 0; mi < FR; mi++)
        af[mi] = *(const bf16x8*)&LDS_[buf*(BM*LR) + (wm + mi*16 + lr)*LR + kk*32 + lg*8];
      #pragma unroll
      for (int ni = 0; ni < FC; ni++)
        bfv[ni] = *(const bf16x8*)&LDS_[2*BM*LR + buf*(BN*LR) + (wn + ni*16 + lr)*LR + kk*32 + lg*8];
      #pragma unroll
      for (int mi = 0; mi < FR; mi++)
        #pragma unroll
        for (int ni = 0; ni < FC; ni++)
          acc[mi][ni] = __builtin_amdgcn_mfma_f32_16x16x32_bf16(af[mi], bfv[ni], acc[mi][ni], 0, 0, 0);
    }
  };

  const int nk = K >> 6;
  LOADT(0);
  WRITE(0);
  if (nk > 1) LOADT(1);
  __syncthreads();
  for (int kt = 0; kt < nk; kt++){
    COMPUTE(kt & 1);
    if (kt + 1 < nk){
      __syncthreads();
      WRITE((kt + 1) & 1);
      if (kt + 2 < nk) LOADT(kt + 2);
      __syncthreads();
    }
  }

  // ---- epilogue: C/D layout col=lane&15, row=(lane>>4)*4+e ----
  float bv[FC];
  #pragma unroll
  for (int ni = 0; ni < FC; ni++){
    int c = nBase + wn + ni*16 + lr;
    bv[ni] = (bi >= 0 && c < Ncols) ? ldin(bias, boff + c, fb) : 0.f;
  }
  #pragma unroll
  for (int mi = 0; mi < FR; mi++){
    #pragma unroll
    for (int e = 0; e < 4; e++){
      int rrow = mBase + wm + mi*16 + lg*4 + e;
      if (rrow >= M) continue;
      #pragma unroll
      for (int ni = 0; ni < FC; ni++){
        int c = nBase + wn + ni*16 + lr;
        if (c >= Ncols) continue;
        float v = acc[mi][ni][e] + bv[ni];
        if (ACT==1) v = 0.5f*v*(1.f + erff(v*0.70710678118f));
        if (ACCUM){ float* cp = (float*)&C[(long)rrow*ldc + c]; *cp += v; }
        else stf(&C[(long)rrow*ldc + c], v);
      }
    }
  }
}

// ---- assemble residual stream ----------------------------------------------
__global__ void assemble_t(const float* __restrict__ pe,
                           const void* __restrict__ bpe, const void* __restrict__ cls,
                           const void* __restrict__ pos, const int* __restrict__ F,
                           float* __restrict__ T)
{
  int f2 = F[2], f3 = F[3], f4 = F[4];
  int idx = blockIdx.x*256 + threadIdx.x;
  if (idx >= TOKENS*Dm) return;
  int d = idx % Dm;
  int t = idx / Dm;
  int n = t % Ntok, b = t / Ntok;
  float v;
  if (n == 0) v = ldin(cls, d, f3);
  else        v = pe[((long)b*NPATCH + n-1)*Dm + d] + ldin(bpe, d, f2);
  T[idx] = v + ldin(pos, (long)n*Dm + d, f4);
}

// ---- layernorm --------------------------------------------------------------
__global__ void layernorm(const float* __restrict__ X, long xstride,
                          const void* __restrict__ g, long goff, int gi,
                          const void* __restrict__ b, long boff, int bi,
                          const int* __restrict__ F,
                          float* __restrict__ Y, long ystride)
{
  int fg = F[gi], fb = F[bi];
  int row = blockIdx.x;
  const float* xr = X + (long)row*xstride;
  float* yr = Y + (long)row*ystride;
  int tid = threadIdx.x;
  float x0 = xr[tid], x1 = xr[tid+256], x2 = xr[tid+512];
  float s  = x0+x1+x2;
  float sq = x0*x0 + x1*x1 + x2*x2;
  __shared__ float red[6][2];
  for (int off=32; off; off>>=1){ s += __shfl_down(s, off); sq += __shfl_down(sq, off); }
  int wave = tid >> 6, lane = tid & 63;
  if (lane==0){ red[wave][0]=s; red[wave][1]=sq; }
  __syncthreads();
  if (tid==0){
    float S=0, SQ=0;
    for (int w=0;w<4;w++){ S+=red[w][0]; SQ+=red[w][1]; }
    red[4][0] = S*(1.f/768.f);
    red[4][1] = SQ*(1.f/768.f);
  }
  __syncthreads();
  float m  = red[4][0];
  float var= red[4][1] - m*m;
  float rs = rsqrtf(var + 1e-6f);
  yr[tid]     = (x0-m)*rs*ldin(g,goff+tid,fg)     + ldin(b,boff+tid,fb);
  yr[tid+256] = (x1-m)*rs*ldin(g,goff+tid+256,fg) + ldin(b,boff+tid+256,fb);
  yr[tid+512] = (x2-m)*rs*ldin(g,goff+tid+512,fg) + ldin(b,boff+tid+512,fb);
}

// ---- fused talking-heads attention ------------------------------------------
#define SMP 232            /* m-pad: 464B row stride, 16B aligned */
#define VROW 776           /* V LDS row: 1552B, 16B aligned */

__device__ __forceinline__ void mix12(bf16 (*S)[16][SMP], const void* W, long woff,
                                      int fw, int tid){
  float wf[12][12];
  #pragma unroll
  for (int g=0; g<12; g++)
    #pragma unroll
    for (int h=0; h<12; h++) wf[g][h] = ldin(W, woff + g*12 + h, fw);
  for (int it=0; it<13; it++){
    int p = it*256 + tid;          // 13*256 = 3328 = 16*208
    int n = p / 208, m = p - n*208;
    float vals[12];
    #pragma unroll
    for (int h=0; h<12; h++) vals[h] = b2f(S[h][n][m]);
    #pragma unroll
    for (int g=0; g<12; g++){
      float s = 0.f;
      #pragma unroll
      for (int h=0; h<12; h++) s += vals[h]*wf[g][h];
      S[g][n][m] = __float2bfloat16(s);
    }
  }
}

__global__ __launch_bounds__(256, 1)
void attn_fused(const bf16* __restrict__ QKV,
                const void* __restrict__ Wpre, const void* __restrict__ Wpost,
                long woff, const int* __restrict__ F, float* __restrict__ O)
{
  __shared__ __align__(16) bf16 S[12][16][SMP];     // 89,088 B
  __shared__ __align__(16) bf16 Vl[32][VROW];       // 49,664 B
  const int b  = blockIdx.y;
  const int n0 = blockIdx.x * 16;
  const int tid = threadIdx.x, lane = tid & 63, wave = tid >> 6;
  const int lr = lane & 15, lg = lane >> 4;
  const bf16* Qb = QKV + (long)b*Ntok*2304;

  {
    bf16x8 z = {};
    bf16x8* sp = (bf16x8*)S;
    for (int i = tid; i < (12*16*SMP)/8; i += 256) sp[i] = z;
  }

  bf16x8 qf[3][2] = {};
  int nq = n0 + lr;
  if (nq < Ntok){
    #pragma unroll
    for (int hh=0; hh<3; hh++){
      int h = wave*3 + hh;
      qf[hh][0] = *(const bf16x8*)(Qb + (long)nq*2304 + h*64 +      lg*8);
      qf[hh][1] = *(const bf16x8*)(Qb + (long)nq*2304 + h*64 + 32 + lg*8);
    }
  }
  __syncthreads();

  // ---- phase 1: scores ----
  {
    const bf16* Kb = Qb + Dm;
    for (int mt=0; mt<13; mt++){
      int mq = mt*16 + lr;
      bool mok = (mq < Ntok);
      #pragma unroll
      for (int hh=0; hh<3; hh++){
        int h = wave*3 + hh;
        bf16x8 k0 = {}, k1 = {};
        if (mok){
          k0 = *(const bf16x8*)(Kb + (long)mq*2304 + h*64 +      lg*8);
          k1 = *(const bf16x8*)(Kb + (long)mq*2304 + h*64 + 32 + lg*8);
        }
        f32x4 acc = {};
        acc = __builtin_amdgcn_mfma_f32_16x16x32_bf16(qf[hh][0], k0, acc, 0,0,0);
        acc = __builtin_amdgcn_mfma_f32_16x16x32_bf16(qf[hh][1], k1, acc, 0,0,0);
        #pragma unroll
        for (int e=0; e<4; e++)
          S[h][lg*4+e][mt*16+lr] = __float2bfloat16(SCALE*acc[e]);
      }
    }
  }
  __syncthreads();

  mix12(S, Wpre, woff, F[9], tid);
  __syncthreads();

  // ---- softmax ----
  for (int i=0; i<48; i++){
    int r = wave*48 + i;
    int g = r >> 4, nl = r & 15;
    if (n0 + nl >= Ntok) continue;
    float v[4]; float mx = -1e30f;
    #pragma unroll
    for (int j=0; j<4; j++){
      int m = lane + j*64;
      v[j] = (m < Ntok) ? b2f(S[g][nl][m]) : -1e30f;
      mx = fmaxf(mx, v[j]);
    }
    for (int off=32; off; off>>=1) mx = fmaxf(mx, __shfl_xor(mx, off));
    float s = 0.f;
    #pragma unroll
    for (int j=0; j<4; j++){ v[j] = __expf(v[j]-mx); s += v[j]; }
    for (int off=32; off; off>>=1) s += __shfl_xor(s, off);
    float inv = 1.f/s;
    #pragma unroll
    for (int j=0; j<4; j++){
      int m = lane + j*64;
      if (m < Ntok) S[g][nl][m] = __float2bfloat16(v[j]*inv);
    }
  }
  __syncthreads();

  mix12(S, Wpost, woff, F[10], tid);
  __syncthreads();

  // ---- AV ----
  const bf16* Vg = Qb + 2*Dm;
  f32x4 avacc[3][4] = {};
  for (int mc=0; mc<7; mc++){
    int m0 = mc*32;
    for (int it=0; it<12; it++){
      int e = it*64 + lane;
      int ml = wave*8 + e/96;
      int grp = e - (e/96)*96;
      int mg = m0 + ml;
      bf16x8 v = {};
      if (mg < Ntok) v = *(const bf16x8*)(Vg + (long)mg*2304 + grp*8);
      int off = ml*(VROW*2) + grp*16;
      off ^= ((ml>>3)&3) << 5;
      *(bf16x8*)((char*)Vl + off) = v;
    }
    __syncthreads();
    #pragma unroll
    for (int hh=0; hh<3; hh++){
      int h = wave*3 + hh;
      bf16x8 af = *(const bf16x8*)&S[h][lr][m0 + lg*8];
      #pragma unroll
      for (int dt=0; dt<4; dt++){
        int dcol = h*64 + dt*16 + lr;
        bf16x8 bfv;
        #pragma unroll
        for (int j=0; j<8; j++){
          int ml = lg*8 + j;
          int off = ml*(VROW*2) + dcol*2;
          off ^= ((ml>>3)&3) << 5;
          bfv[j] = *(short*)((char*)Vl + off);
        }
        avacc[hh][dt] = __builtin_amdgcn_mfma_f32_16x16x32_bf16(af, bfv, avacc[hh][dt], 0,0,0);
      }
    }
    __syncthreads();
  }

  #pragma unroll
  for (int hh=0; hh<3; hh++){
    int h = wave*3 + hh;
    #pragma unroll
    for (int dt=0; dt<4; dt++){
      #pragma unroll
      for (int e=0; e<4; e++){
        int n = n0 + lg*4 + e;
        if (n < Ntok)
          O[((long)(b*Ntok + n))*Dm + h*64 + dt*16 + lr] = avacc[hh][dt][e];
      }
    }
  }
}

// ---- head: out[b,c] = lnf(t[b,0]) . head_w[c,:] + head_b[c] -----------------
__global__ void head_gemm(const float* __restrict__ HF, const void* __restrict__ Wh,
                          const void* __restrict__ bh_, const int* __restrict__ F,
                          float* __restrict__ out){
  int fw = F[21], fb = F[22];
  int b = blockIdx.y;
  int c = blockIdx.x*256 + threadIdx.x;
  __shared__ float hs[Dm];
  for (int i=threadIdx.x; i<Dm; i+=256) hs[i] = HF[(long)b*Dm+i];
  __syncthreads();
  if (c >= NC) return;
  float s = ldin(bh_, c, fb);
  for (int k=0;k<Dm;k++) s += hs[k]*ldin(Wh, (long)c*Dm + k, fw);
  out[b*NC + c] = s;
}

extern "C" void kernel_launch(void* const* d_in, const int* in_sizes, int n_in,
                              void* d_out, int out_size, void* d_ws, size_t ws_size,
                              hipStream_t stream)
{
  static const int EXP[23] = {4816896, 589824, 768, 768, 151296, 9216, 9216,
                              21233664, 27648, 1728, 1728, 7077888, 9216, 9216,
                              9216, 28311552, 36864, 28311552, 9216, 768, 768,
                              768000, 1000};
  const void* in[23];
  bool ident = (n_in == 23);
  if (ident) for (int i = 0; i < 23; i++) if (in_sizes[i] != EXP[i]) { ident = false; break; }
  if (ident) {
    for (int i = 0; i < 23; i++) in[i] = d_in[i];
  } else {
    bool used[64] = {};
    for (int i = 0; i < 23; i++){
      in[i] = d_in[i < n_in ? i : 0];
      for (int j = 0; j < n_in && j < 64; j++)
        if (!used[j] && in_sizes[j] == EXP[i]) { in[i] = d_in[j]; used[j] = true; break; }
    }
  }

  float* out = (float*)d_out;

  char* base = (char*)d_ws;
  int*   Fl  = (int*)base;
  float* T   = (float*)(base + 256);
  float* Hb  = (float*)(base + 19366144L);
  char*  REST=  base + 38732032L;
  float* XP  = (float*)REST;
  bf16*  QKV = (bf16*)REST;
  bf16*  M1  = (bf16*)REST;

  P23 ptrs;
  for (int i = 0; i < 23; i++) ptrs.p[i] = in[i];
  detect_k<<<23, 64, 0, stream>>>(ptrs, Fl);

  patch_extract<<<(Bb*NPATCH*Dm+255)/256, 256, 0, stream>>>(in[0], Fl, XP);
  gemm_mfma<64,64,0,false,float,float><<<dim3(Dm/64, (Bb*NPATCH)/64), 256, 0, stream>>>(
      XP, Dm, in[1], 0, Dm, nullptr, 0, Fl, 1, -1, Hb, Dm, Bb*NPATCH, Dm, Dm);
  assemble_t<<<(TOKENS*Dm+255)/256, 256, 0, stream>>>(Hb, in[2], in[3], in[4], Fl, T);

  for (int L=0; L<DEPTH; L++){
    layernorm<<<TOKENS, 256, 0, stream>>>(T, Dm, in[5], (long)L*Dm, 5,
                                          in[6], (long)L*Dm, 6, Fl, Hb, Dm);
    gemm_mfma<128,128,0,false,float,bf16><<<dim3(2304/128, (TOKENS+127)/128), 256, 0, stream>>>(
        Hb, Dm, in[7], (long)L*2304*Dm, Dm, in[8], (long)L*2304, Fl, 7, 8,
        QKV, 2304, TOKENS, 2304, Dm);
    attn_fused<<<dim3(13, Bb), 256, 0, stream>>>(QKV, in[9], in[10],
                                                 (long)L*Hn*Hn, Fl, Hb);
    gemm_mfma<64,64,0,true,float,float><<<dim3(Dm/64, (TOKENS+63)/64), 256, 0, stream>>>(
        Hb, Dm, in[11], (long)L*Dm*Dm, Dm, in[12], (long)L*Dm, Fl, 11, 12,
        T, Dm, TOKENS, Dm, Dm);
    layernorm<<<TOKENS, 256, 0, stream>>>(T, Dm, in[13], (long)L*Dm, 13,
                                          in[14], (long)L*Dm, 14, Fl, Hb, Dm);
    gemm_mfma<128,128,1,false,float,bf16><<<dim3(MLPD/128, (TOKENS+127)/128), 256, 0, stream>>>(
        Hb, Dm, in[15], (long)L*MLPD*Dm, Dm, in[16], (long)L*MLPD, Fl, 15, 16,
        M1, MLPD, TOKENS, MLPD, Dm);
    gemm_mfma<64,64,0,true,bf16,float><<<dim3(Dm/64, (TOKENS+63)/64), 256, 0, stream>>>(
        M1, MLPD, in[17], (long)L*Dm*MLPD, MLPD, in[18], (long)L*Dm, Fl, 17, 18,
        T, Dm, TOKENS, Dm, MLPD);
  }

  layernorm<<<Bb, 256, 0, stream>>>(T, (long)Ntok*Dm, in[19], 0, 19,
                                    in[20], 0, 20, Fl, Hb, Dm);
  head_gemm<<<dim3((NC+255)/256, Bb), 256, 0, stream>>>(Hb, in[21], in[22], Fl, out);
}

// Round 5
// 5829.160 us; speedup vs baseline: 8.2708x; 1.8037x over previous
//
#include <hip/hip_runtime.h>
#include <hip/hip_bf16.h>
#include <math.h>

#define Dm 768
#define Hn 12
#define DEPTH 12
#define NPATCH 196
#define Ntok 197
#define MLPD 3072
#define NC 1000
#define Bb 32
#define HD 64
#define SCALE 0.125f
#define TOKENS (Bb*Ntok)      /* 6304 */

typedef __hip_bfloat16 bf16;
typedef __attribute__((ext_vector_type(8))) short bf16x8;
typedef __attribute__((ext_vector_type(4))) float f32x4;

__device__ __forceinline__ float b2f(bf16 x){ return __bfloat162float(x); }
__device__ __forceinline__ float bits2f(unsigned short u){
  union { float f; unsigned int i; } cv; cv.i = ((unsigned int)u) << 16; return cv.f;
}
__device__ __forceinline__ void  stf(float* p, float v){ *p = v; }
__device__ __forceinline__ void  stf(bf16*  p, float v){ *p = __float2bfloat16(v); }

// Runtime-dtype input accessor: f==1 -> bf16, f==0 -> fp32.
__device__ __forceinline__ float ldin(const void* p, long i, int f){
  return f ? __bfloat162float(((const bf16*)p)[i]) : ((const float*)p)[i];
}

__device__ __forceinline__ unsigned short f2bfu(float v){
  bf16 b = __float2bfloat16(v);
  return *(unsigned short*)&b;
}
__device__ __forceinline__ bf16x8 pack8(const float4& a, const float4& b){
  bf16x8 r;
  r[0]=(short)f2bfu(a.x); r[1]=(short)f2bfu(a.y); r[2]=(short)f2bfu(a.z); r[3]=(short)f2bfu(a.w);
  r[4]=(short)f2bfu(b.x); r[5]=(short)f2bfu(b.y); r[6]=(short)f2bfu(b.z); r[7]=(short)f2bfu(b.w);
  return r;
}

struct P23 { const void* p[23]; };

// ---- per-input dtype detection ---------------------------------------------
__global__ void detect_k(P23 ptrs, int* __restrict__ flags){
  int b = blockIdx.x;
  const unsigned short* u = (const unsigned short*)ptrs.p[b];
  int lane = threadIdx.x;
  unsigned short v = u[lane];
  int ex = (v >> 7) & 0xFF;
  bool bad = (ex > 140) || (ex != 0 && ex < 90);
  bool isz = (v == 0);
  unsigned long long bb = __ballot(bad);
  unsigned long long zb = __ballot(isz);
  if (lane == 0)
    flags[b] = (bb != 0ULL || zb == 0x5555555555555555ULL) ? 0 : 1;
}

// ---- weight pre-conversion to bf16 ------------------------------------------
// one layer's {qkv,proj,fc1,fc2} -> contiguous bf16 slot
__global__ void convert_layer(P23 ptrs, const int* __restrict__ F, int L,
                              bf16* __restrict__ dst){
  long idx = ((long)blockIdx.x*256 + threadIdx.x)*8;
  if (idx >= 7077888L) return;
  const void* src; int f; long so;
  if (idx < 1769472L)      { src=ptrs.p[7];  f=F[7];  so=(long)L*1769472L + idx; }
  else if (idx < 2359296L) { src=ptrs.p[11]; f=F[11]; so=(long)L*589824L  + (idx-1769472L); }
  else if (idx < 4718592L) { src=ptrs.p[15]; f=F[15]; so=(long)L*2359296L + (idx-2359296L); }
  else                     { src=ptrs.p[17]; f=F[17]; so=(long)L*2359296L + (idx-4718592L); }
  bf16x8 v;
  if (f) v = *(const bf16x8*)((const bf16*)src + so);
  else {
    const float* s = (const float*)src + so;
    v = pack8(*(const float4*)s, *(const float4*)(s+4));
  }
  *(bf16x8*)(dst + idx) = v;
}

__global__ void convert_arr(const void* __restrict__ src, const int* __restrict__ F,
                            int fi, long n, bf16* __restrict__ dst){
  long idx = ((long)blockIdx.x*256 + threadIdx.x)*8;
  if (idx >= n) return;
  int f = F[fi];
  bf16x8 v;
  if (f) v = *(const bf16x8*)((const bf16*)src + idx);
  else {
    const float* s = (const float*)src + idx;
    v = pack8(*(const float4*)s, *(const float4*)(s+4));
  }
  *(bf16x8*)(dst + idx) = v;
}

// ---- patch extraction: x[B,3,224,224] -> xp[B*196, 768] bf16 ----------------
__global__ void patch_extract(const void* __restrict__ x, const int* __restrict__ F,
                              bf16* __restrict__ xp){
  int fx = F[0];
  int idx = blockIdx.x*256 + threadIdx.x;
  if (idx >= Bb*NPATCH*Dm) return;
  int k = idx % Dm;
  int t = idx / Dm;
  int p = t % NPATCH; int b = t / NPATCH;
  int c  = k >> 8;
  int r  = (k >> 4) & 15;
  int cc = k & 15;
  int pi = p / 14, pj = p % 14;
  long src = ((long)(b*3 + c)*224 + pi*16 + r)*224 + pj*16 + cc;
  xp[idx] = __float2bfloat16(ldin(x, src, fx));
}

// ---- MFMA GEMM: C[M,N] = (A[M,K] @ W[N,K]^T) + bias -------------------------
// A always bf16. BK=32 double-buffered, LDS stride 40 elem (80B): read banks
// advance 20/row -> worst 2-way (free); write pattern 2-way. 128^2 tile LDS
// = 40960B -> 4 blocks/CU; 64^2 -> 20480B -> 6+ blocks/CU.
template<int BM, int BN, int ACT, bool ACCUM, bool WBF16, typename TC>
__global__ __launch_bounds__(256, (BM==64)?6:4)
void gemm_mfma(const bf16* __restrict__ A, int lda,
               const void* __restrict__ W, long woff, int ldw,
               const void* __restrict__ bias, long boff,
               const int* __restrict__ F, int wi, int bi,
               TC* __restrict__ C, int ldc,
               int M, int Ncols, int K)
{
  constexpr int FR = BM/32, FCn = BN/32;
  constexpr int LR = 40;
  constexpr int RA = BM/64, RW = BN/64;
  __shared__ __align__(16) bf16 LDS_[2*(BM+BN)*LR];

  const int fw = WBF16 ? 1 : F[wi];
  const int fb = (bi >= 0) ? F[bi] : 0;
  const int tid = threadIdx.x, lane = tid & 63, wave = tid >> 6;
  const int mBase = blockIdx.y*BM, nBase = blockIdx.x*BN;
  const int wm = (wave >> 1)*(BM/2), wn = (wave & 1)*(BN/2);
  const int lr = lane & 15, lg = lane >> 4;
  const int srow = tid >> 2, scol = (tid & 3)*8;

  f32x4 acc[FR][FCn] = {};
  bf16x8 ra[RA], rwh[RW];
  float4 rwf[RW][2];

  auto LOADT = [&](int kt){
    const int k0 = kt*32 + scol;
    #pragma unroll
    for (int i = 0; i < RA; i++){
      int gm = mBase + srow + i*64;
      ra[i] = (bf16x8){};
      if (gm < M) ra[i] = *(const bf16x8*)(A + (long)gm*lda + k0);
    }
    #pragma unroll
    for (int i = 0; i < RW; i++){
      int gn = nBase + srow + i*64;
      if (WBF16 || fw){
        rwh[i] = (bf16x8){};
        if (gn < Ncols)
          rwh[i] = *(const bf16x8*)((const bf16*)W + woff + (long)gn*ldw + k0);
      } else {
        rwf[i][0] = make_float4(0.f,0.f,0.f,0.f);
        rwf[i][1] = make_float4(0.f,0.f,0.f,0.f);
        if (gn < Ncols){
          const float* p = (const float*)W + woff + (long)gn*ldw + k0;
          rwf[i][0] = *(const float4*)p;
          rwf[i][1] = *(const float4*)(p+4);
        }
      }
    }
  };

  auto WRITE = [&](int buf){
    #pragma unroll
    for (int i = 0; i < RA; i++)
      *(bf16x8*)&LDS_[buf*(BM*LR) + (srow + i*64)*LR + scol] = ra[i];
    #pragma unroll
    for (int i = 0; i < RW; i++){
      bf16x8 v;
      if (WBF16 || fw) v = rwh[i];
      else             v = pack8(rwf[i][0], rwf[i][1]);
      *(bf16x8*)&LDS_[2*(BM*LR) + buf*(BN*LR) + (srow + i*64)*LR + scol] = v;
    }
  };

  auto COMPUTE = [&](int buf){
    bf16x8 bfv[FCn];
    #pragma unroll
    for (int ni = 0; ni < FCn; ni++)
      bfv[ni] = *(const bf16x8*)&LDS_[2*(BM*LR) + buf*(BN*LR) + (wn + ni*16 + lr)*LR + lg*8];
    #pragma unroll
    for (int mi = 0; mi < FR; mi++){
      bf16x8 af = *(const bf16x8*)&LDS_[buf*(BM*LR) + (wm + mi*16 + lr)*LR + lg*8];
      #pragma unroll
      for (int ni = 0; ni < FCn; ni++)
        acc[mi][ni] = __builtin_amdgcn_mfma_f32_16x16x32_bf16(af, bfv[ni], acc[mi][ni], 0, 0, 0);
    }
  };

  const int nk = K >> 5;
  LOADT(0); WRITE(0);
  if (nk > 1) LOADT(1);
  __syncthreads();
  for (int kt = 0; kt < nk; kt++){
    COMPUTE(kt & 1);
    if (kt + 1 < nk){
      __syncthreads();
      WRITE((kt + 1) & 1);
      if (kt + 2 < nk) LOADT(kt + 2);
      __syncthreads();
    }
  }

  // ---- epilogue: C/D layout col=lane&15, row=(lane>>4)*4+e ----
  float bv[FCn];
  #pragma unroll
  for (int ni = 0; ni < FCn; ni++){
    int c = nBase + wn + ni*16 + lr;
    bv[ni] = (bi >= 0 && c < Ncols) ? ldin(bias, boff + c, fb) : 0.f;
  }
  #pragma unroll
  for (int mi = 0; mi < FR; mi++){
    #pragma unroll
    for (int e = 0; e < 4; e++){
      int rrow = mBase + wm + mi*16 + lg*4 + e;
      if (rrow >= M) continue;
      #pragma unroll
      for (int ni = 0; ni < FCn; ni++){
        int c = nBase + wn + ni*16 + lr;
        if (c >= Ncols) continue;
        float v = acc[mi][ni][e] + bv[ni];
        if (ACT==1) v = 0.5f*v*(1.f + erff(v*0.70710678118f));
        if (ACCUM){ float* cp = (float*)&C[(long)rrow*ldc + c]; *cp += v; }
        else stf(&C[(long)rrow*ldc + c], v);
      }
    }
  }
}

// ---- assemble residual stream ----------------------------------------------
__global__ void assemble_t(const float* __restrict__ pe,
                           const void* __restrict__ bpe, const void* __restrict__ cls,
                           const void* __restrict__ pos, const int* __restrict__ F,
                           float* __restrict__ T)
{
  int f2 = F[2], f3 = F[3], f4 = F[4];
  int idx = blockIdx.x*256 + threadIdx.x;
  if (idx >= TOKENS*Dm) return;
  int d = idx % Dm;
  int t = idx / Dm;
  int n = t % Ntok, b = t / Ntok;
  float v;
  if (n == 0) v = ldin(cls, d, f3);
  else        v = pe[((long)b*NPATCH + n-1)*Dm + d] + ldin(bpe, d, f2);
  T[idx] = v + ldin(pos, (long)n*Dm + d, f4);
}

// ---- layernorm (templated output dtype) -------------------------------------
template<typename TY>
__global__ void layernorm(const float* __restrict__ X, long xstride,
                          const void* __restrict__ g, long goff, int gi,
                          const void* __restrict__ b, long boff, int bi,
                          const int* __restrict__ F,
                          TY* __restrict__ Y, long ystride)
{
  int fg = F[gi], fb = F[bi];
  int row = blockIdx.x;
  const float* xr = X + (long)row*xstride;
  TY* yr = Y + (long)row*ystride;
  int tid = threadIdx.x;
  float x0 = xr[tid], x1 = xr[tid+256], x2 = xr[tid+512];
  float s  = x0+x1+x2;
  float sq = x0*x0 + x1*x1 + x2*x2;
  __shared__ float red[6][2];
  for (int off=32; off; off>>=1){ s += __shfl_down(s, off); sq += __shfl_down(sq, off); }
  int wave = tid >> 6, lane = tid & 63;
  if (lane==0){ red[wave][0]=s; red[wave][1]=sq; }
  __syncthreads();
  if (tid==0){
    float S=0, SQ=0;
    for (int w=0;w<4;w++){ S+=red[w][0]; SQ+=red[w][1]; }
    red[4][0] = S*(1.f/768.f);
    red[4][1] = SQ*(1.f/768.f);
  }
  __syncthreads();
  float m  = red[4][0];
  float var= red[4][1] - m*m;
  float rs = rsqrtf(var + 1e-6f);
  stf(&yr[tid],     (x0-m)*rs*ldin(g,goff+tid,fg)     + ldin(b,boff+tid,fb));
  stf(&yr[tid+256], (x1-m)*rs*ldin(g,goff+tid+256,fg) + ldin(b,boff+tid+256,fb));
  stf(&yr[tid+512], (x2-m)*rs*ldin(g,goff+tid+512,fg) + ldin(b,boff+tid+512,fb));
}

// ---- fused talking-heads attention ------------------------------------------
#define SMP 232            /* m-pad: 464B row stride, 16B aligned */
#define VROW 776           /* V LDS row: 1552B, 16B aligned */

__device__ __forceinline__ void mix12(bf16 (*S)[16][SMP], const void* W, long woff,
                                      int fw, int tid){
  float wf[12][12];
  #pragma unroll
  for (int g=0; g<12; g++)
    #pragma unroll
    for (int h=0; h<12; h++) wf[g][h] = ldin(W, woff + g*12 + h, fw);
  for (int it=0; it<13; it++){
    int p = it*256 + tid;          // 13*256 = 3328 = 16*208
    int n = p / 208, m = p - n*208;
    float vals[12];
    #pragma unroll
    for (int h=0; h<12; h++) vals[h] = b2f(S[h][n][m]);
    #pragma unroll
    for (int g=0; g<12; g++){
      float s = 0.f;
      #pragma unroll
      for (int h=0; h<12; h++) s += vals[h]*wf[g][h];
      S[g][n][m] = __float2bfloat16(s);
    }
  }
}

__global__ __launch_bounds__(256, 1)
void attn_fused(const bf16* __restrict__ QKV,
                const void* __restrict__ Wpre, const void* __restrict__ Wpost,
                long woff, const int* __restrict__ F, bf16* __restrict__ O)
{
  __shared__ __align__(16) bf16 S[12][16][SMP];     // 89,088 B
  __shared__ __align__(16) bf16 Vl[32][VROW];       // 49,664 B
  const int b  = blockIdx.y;
  const int n0 = blockIdx.x * 16;
  const int tid = threadIdx.x, lane = tid & 63, wave = tid >> 6;
  const int lr = lane & 15, lg = lane >> 4;
  const bf16* Qb = QKV + (long)b*Ntok*2304;

  {
    bf16x8 z = {};
    bf16x8* sp = (bf16x8*)S;
    for (int i = tid; i < (12*16*SMP)/8; i += 256) sp[i] = z;
  }

  bf16x8 qf[3][2] = {};
  int nq = n0 + lr;
  if (nq < Ntok){
    #pragma unroll
    for (int hh=0; hh<3; hh++){
      int h = wave*3 + hh;
      qf[hh][0] = *(const bf16x8*)(Qb + (long)nq*2304 + h*64 +      lg*8);
      qf[hh][1] = *(const bf16x8*)(Qb + (long)nq*2304 + h*64 + 32 + lg*8);
    }
  }
  __syncthreads();

  // ---- phase 1: scores ----
  {
    const bf16* Kb = Qb + Dm;
    for (int mt=0; mt<13; mt++){
      int mq = mt*16 + lr;
      bool mok = (mq < Ntok);
      #pragma unroll
      for (int hh=0; hh<3; hh++){
        int h = wave*3 + hh;
        bf16x8 k0 = {}, k1 = {};
        if (mok){
          k0 = *(const bf16x8*)(Kb + (long)mq*2304 + h*64 +      lg*8);
          k1 = *(const bf16x8*)(Kb + (long)mq*2304 + h*64 + 32 + lg*8);
        }
        f32x4 acc = {};
        acc = __builtin_amdgcn_mfma_f32_16x16x32_bf16(qf[hh][0], k0, acc, 0,0,0);
        acc = __builtin_amdgcn_mfma_f32_16x16x32_bf16(qf[hh][1], k1, acc, 0,0,0);
        #pragma unroll
        for (int e=0; e<4; e++)
          S[h][lg*4+e][mt*16+lr] = __float2bfloat16(SCALE*acc[e]);
      }
    }
  }
  __syncthreads();

  mix12(S, Wpre, woff, F[9], tid);
  __syncthreads();

  // ---- softmax ----
  for (int i=0; i<48; i++){
    int r = wave*48 + i;
    int g = r >> 4, nl = r & 15;
    if (n0 + nl >= Ntok) continue;
    float v[4]; float mx = -1e30f;
    #pragma unroll
    for (int j=0; j<4; j++){
      int m = lane + j*64;
      v[j] = (m < Ntok) ? b2f(S[g][nl][m]) : -1e30f;
      mx = fmaxf(mx, v[j]);
    }
    for (int off=32; off; off>>=1) mx = fmaxf(mx, __shfl_xor(mx, off));
    float s = 0.f;
    #pragma unroll
    for (int j=0; j<4; j++){ v[j] = __expf(v[j]-mx); s += v[j]; }
    for (int off=32; off; off>>=1) s += __shfl_xor(s, off);
    float inv = 1.f/s;
    #pragma unroll
    for (int j=0; j<4; j++){
      int m = lane + j*64;
      if (m < Ntok) S[g][nl][m] = __float2bfloat16(v[j]*inv);
    }
  }
  __syncthreads();

  mix12(S, Wpost, woff, F[10], tid);
  __syncthreads();

  // ---- AV ----
  const bf16* Vg = Qb + 2*Dm;
  f32x4 avacc[3][4] = {};
  for (int mc=0; mc<7; mc++){
    int m0 = mc*32;
    for (int it=0; it<12; it++){
      int e = it*64 + lane;
      int ml = wave*8 + e/96;
      int grp = e - (e/96)*96;
      int mg = m0 + ml;
      bf16x8 v = {};
      if (mg < Ntok) v = *(const bf16x8*)(Vg + (long)mg*2304 + grp*8);
      int off = ml*(VROW*2) + grp*16;
      off ^= ((ml>>3)&3) << 5;
      *(bf16x8*)((char*)Vl + off) = v;
    }
    __syncthreads();
    #pragma unroll
    for (int hh=0; hh<3; hh++){
      int h = wave*3 + hh;
      bf16x8 af = *(const bf16x8*)&S[h][lr][m0 + lg*8];
      #pragma unroll
      for (int dt=0; dt<4; dt++){
        int dcol = h*64 + dt*16 + lr;
        bf16x8 bfv;
        #pragma unroll
        for (int j=0; j<8; j++){
          int ml = lg*8 + j;
          int off = ml*(VROW*2) + dcol*2;
          off ^= ((ml>>3)&3) << 5;
          bfv[j] = *(short*)((char*)Vl + off);
        }
        avacc[hh][dt] = __builtin_amdgcn_mfma_f32_16x16x32_bf16(af, bfv, avacc[hh][dt], 0,0,0);
      }
    }
    __syncthreads();
  }

  #pragma unroll
  for (int hh=0; hh<3; hh++){
    int h = wave*3 + hh;
    #pragma unroll
    for (int dt=0; dt<4; dt++){
      #pragma unroll
      for (int e=0; e<4; e++){
        int n = n0 + lg*4 + e;
        if (n < Ntok)
          O[((long)(b*Ntok + n))*Dm + h*64 + dt*16 + lr] = __float2bfloat16(avacc[hh][dt][e]);
      }
    }
  }
}

// ---- head: out[b,c] = lnf(t[b,0]) . head_w[c,:] + head_b[c] -----------------
__global__ void head_gemm(const float* __restrict__ HF, const void* __restrict__ Wh,
                          const void* __restrict__ bh_, const int* __restrict__ F,
                          float* __restrict__ out){
  int fw = F[21], fb = F[22];
  int b = blockIdx.y;
  int c = blockIdx.x*256 + threadIdx.x;
  __shared__ float hs[Dm];
  for (int i=threadIdx.x; i<Dm; i+=256) hs[i] = HF[(long)b*Dm+i];
  __syncthreads();
  if (c >= NC) return;
  float s = ldin(bh_, c, fb);
  for (int k=0;k<Dm;k++) s += hs[k]*ldin(Wh, (long)c*Dm + k, fw);
  out[b*NC + c] = s;
}

extern "C" void kernel_launch(void* const* d_in, const int* in_sizes, int n_in,
                              void* d_out, int out_size, void* d_ws, size_t ws_size,
                              hipStream_t stream)
{
  static const int EXP[23] = {4816896, 589824, 768, 768, 151296, 9216, 9216,
                              21233664, 27648, 1728, 1728, 7077888, 9216, 9216,
                              9216, 28311552, 36864, 28311552, 9216, 768, 768,
                              768000, 1000};
  const void* in[23];
  bool ident = (n_in == 23);
  if (ident) for (int i = 0; i < 23; i++) if (in_sizes[i] != EXP[i]) { ident = false; break; }
  if (ident) {
    for (int i = 0; i < 23; i++) in[i] = d_in[i];
  } else {
    bool used[64] = {};
    for (int i = 0; i < 23; i++){
      in[i] = d_in[i < n_in ? i : 0];
      for (int j = 0; j < n_in && j < 64; j++)
        if (!used[j] && in_sizes[j] == EXP[i]) { in[i] = d_in[j]; used[j] = true; break; }
    }
  }

  float* out = (float*)d_out;

  // ---- workspace layout ----
  char* base = (char*)d_ws;
  long oo = 0;
  auto alc = [&](long sz){ long r = oo; oo = (oo + sz + 255) & ~255L; return r; };
  long oF  = alc(256);
  long oT  = alc((long)TOKENS*Dm*4);          // fp32 residual
  long oH  = alc((long)TOKENS*Dm*2);          // bf16 hidden (LN out / attn out); head reuses as fp32 (32 rows)
  long oSH = alc((long)TOKENS*MLPD*2);        // shared: XPb+PE / QKV / M1
  long oW0 = 0, oW1 = 0, oWp = 0;
  bool wpre = false;
  {
    long t = oo;
    oW0 = t; t = (t + 7077888L*2 + 255) & ~255L;
    oW1 = t; t = (t + 7077888L*2 + 255) & ~255L;
    oWp = t; t = (t + 589824L*2  + 255) & ~255L;
    wpre = ((size_t)t <= ws_size);
  }

  int*   Fl   = (int*)(base + oF);
  float* T    = (float*)(base + oT);
  bf16*  Hb16 = (bf16*)(base + oH);
  float* Hf   = (float*)(base + oH);          // final-LN fp32 out (Hb16 dead then)
  bf16*  XPb  = (bf16*)(base + oSH);
  float* PE   = (float*)(base + oSH + 9633792L);   // after XPb (aligned: /256 exact)
  bf16*  QKV  = (bf16*)(base + oSH);
  bf16*  M1   = (bf16*)(base + oSH);
  bf16*  Wb0  = (bf16*)(base + oW0);
  bf16*  Wb1  = (bf16*)(base + oW1);
  bf16*  Wp   = (bf16*)(base + oWp);

  P23 ptrs;
  for (int i = 0; i < 23; i++) ptrs.p[i] = in[i];
  detect_k<<<23, 64, 0, stream>>>(ptrs, Fl);

  // ---- patch embed ----
  patch_extract<<<(Bb*NPATCH*Dm+255)/256, 256, 0, stream>>>(in[0], Fl, XPb);
  if (wpre){
    convert_arr<<<(589824/8+255)/256, 256, 0, stream>>>(in[1], Fl, 1, 589824L, Wp);
    convert_layer<<<3456, 256, 0, stream>>>(ptrs, Fl, 0, Wb0);
    gemm_mfma<64,64,0,false,true,float><<<dim3(Dm/64, (Bb*NPATCH+63)/64), 256, 0, stream>>>(
        XPb, Dm, Wp, 0, Dm, nullptr, 0, Fl, 31, -1, PE, Dm, Bb*NPATCH, Dm, Dm);
  } else {
    gemm_mfma<64,64,0,false,false,float><<<dim3(Dm/64, (Bb*NPATCH+63)/64), 256, 0, stream>>>(
        XPb, Dm, in[1], 0, Dm, nullptr, 0, Fl, 1, -1, PE, Dm, Bb*NPATCH, Dm, Dm);
  }
  assemble_t<<<(TOKENS*Dm+255)/256, 256, 0, stream>>>(PE, in[2], in[3], in[4], Fl, T);

  for (int L=0; L<DEPTH; L++){
    bf16* Wcur = (L & 1) ? Wb1 : Wb0;
    bf16* Wnxt = (L & 1) ? Wb0 : Wb1;
    if (wpre && L+1 < DEPTH)
      convert_layer<<<3456, 256, 0, stream>>>(ptrs, Fl, L+1, Wnxt);

    layernorm<bf16><<<TOKENS, 256, 0, stream>>>(T, Dm, in[5], (long)L*Dm, 5,
                                                in[6], (long)L*Dm, 6, Fl, Hb16, Dm);
    if (wpre)
      gemm_mfma<128,128,0,false,true,bf16><<<dim3(2304/128, (TOKENS+127)/128), 256, 0, stream>>>(
          Hb16, Dm, Wcur, 0L, Dm, in[8], (long)L*2304, Fl, 31, 8,
          QKV, 2304, TOKENS, 2304, Dm);
    else
      gemm_mfma<128,128,0,false,false,bf16><<<dim3(2304/128, (TOKENS+127)/128), 256, 0, stream>>>(
          Hb16, Dm, in[7], (long)L*2304*Dm, Dm, in[8], (long)L*2304, Fl, 7, 8,
          QKV, 2304, TOKENS, 2304, Dm);

    attn_fused<<<dim3(13, Bb), 256, 0, stream>>>(QKV, in[9], in[10],
                                                 (long)L*Hn*Hn, Fl, Hb16);

    if (wpre)
      gemm_mfma<64,64,0,true,true,float><<<dim3(Dm/64, (TOKENS+63)/64), 256, 0, stream>>>(
          Hb16, Dm, Wcur, 1769472L, Dm, in[12], (long)L*Dm, Fl, 31, 12,
          T, Dm, TOKENS, Dm, Dm);
    else
      gemm_mfma<64,64,0,true,false,float><<<dim3(Dm/64, (TOKENS+63)/64), 256, 0, stream>>>(
          Hb16, Dm, in[11], (long)L*Dm*Dm, Dm, in[12], (long)L*Dm, Fl, 11, 12,
          T, Dm, TOKENS, Dm, Dm);

    layernorm<bf16><<<TOKENS, 256, 0, stream>>>(T, Dm, in[13], (long)L*Dm, 13,
                                                in[14], (long)L*Dm, 14, Fl, Hb16, Dm);
    if (wpre)
      gemm_mfma<128,128,1,false,true,bf16><<<dim3(MLPD/128, (TOKENS+127)/128), 256, 0, stream>>>(
          Hb16, Dm, Wcur, 2359296L, Dm, in[16], (long)L*MLPD, Fl, 31, 16,
          M1, MLPD, TOKENS, MLPD, Dm);
    else
      gemm_mfma<128,128,1,false,false,bf16><<<dim3(MLPD/128, (TOKENS+127)/128), 256, 0, stream>>>(
          Hb16, Dm, in[15], (long)L*MLPD*Dm, Dm, in[16], (long)L*MLPD, Fl, 15, 16,
          M1, MLPD, TOKENS, MLPD, Dm);
    if (wpre)
      gemm_mfma<64,64,0,true,true,float><<<dim3(Dm/64, (TOKENS+63)/64), 256, 0, stream>>>(
          M1, MLPD, Wcur, 4718592L, MLPD, in[18], (long)L*Dm, Fl, 31, 18,
          T, Dm, TOKENS, Dm, MLPD);
    else
      gemm_mfma<64,64,0,true,false,float><<<dim3(Dm/64, (TOKENS+63)/64), 256, 0, stream>>>(
          M1, MLPD, in[17], (long)L*Dm*MLPD, MLPD, in[18], (long)L*Dm, Fl, 17, 18,
          T, Dm, TOKENS, Dm, MLPD);
  }

  layernorm<float><<<Bb, 256, 0, stream>>>(T, (long)Ntok*Dm, in[19], 0, 19,
                                           in[20], 0, 20, Fl, Hf, Dm);
  head_gemm<<<dim3((NC+255)/256, Bb), 256, 0, stream>>>(Hf, in[21], in[22], Fl, out);
}